// Round 1
// baseline (583.940 us; speedup 1.0000x reference)
//
#include <hip/hip_runtime.h>
#include <hip/hip_fp16.h>
#include <math.h>

// RotationLayer: out = x + scatter_add over edges of rotated neighbor vectors.
//   t_u = R(+phase) @ x[u]  accumulated into out[v]
//   t_v = R(-phase) @ x[v]  accumulated into out[u]
//
// Round 5:
//  - partition: histogram atomicAdd now doubles as slot reservation (local
//    offset kept in registers, packed (off<<20)|node) -> 2 LDS atomics/edge
//    instead of 4. 2-barrier shuffle scan replaces 18-barrier Hillis-Steele.
//    LDS 44->38 KB => 4 blocks/CU (was 3). int4 edge loads, nontemporal
//    streaming loads/stores so the 4 MB xh table stays L2-resident.
//  - accumulate: 8-deep batched uint4 record loads (was 2) to get enough
//    outstanding memory ops; guarded tail to avoid same-address LDS-atomic
//    serialization.

#define NODE_SHIFT   11
#define BUCKET_NODES 2048
#define MAX_NB       512
#define PART_BLOCK   256
#define EPT          8                       // edges per thread (in registers)
#define EPB          (PART_BLOCK * EPT)      // 2048 edges per block
#define RPB          (2 * EPB)               // 4096 records per block

#define ACC_BLOCK    512
#define ACC_UN       8                       // uint4 loads in flight per thread
#define FIX_SCALE    65536.0f
#define INV_FIX      (1.0f / 65536.0f)

typedef unsigned int uint;
typedef uint  uint4v  __attribute__((ext_vector_type(4)));
typedef uint  uint2v  __attribute__((ext_vector_type(2)));
typedef int   int4v   __attribute__((ext_vector_type(4)));
typedef float float2v __attribute__((ext_vector_type(2)));

static __device__ __forceinline__ uint pack_half2(float a, float b) {
    __half2 h = __floats2half2_rn(a, b);
    union { __half2 h2; uint u; } cvt; cvt.h2 = h; return cvt.u;
}

__global__ __launch_bounds__(256) void rot_make_xh(const float2* __restrict__ x2,
                                                   __half2* __restrict__ xh, int n) {
    int i = blockIdx.x * blockDim.x + threadIdx.x;
    if (i < n) {
        float2 v = x2[i];
        xh[i] = __floats2half2_rn(v.x, v.y);
    }
}

__global__ __launch_bounds__(256) void rot_zero_cursors(uint* __restrict__ cursors, int nb) {
    int i = blockIdx.x * blockDim.x + threadIdx.x;
    if (i < nb) cursors[i] = 0u;
}

__global__ __launch_bounds__(PART_BLOCK, 4) void rot_partition(
    const __half2* __restrict__ xh,
    const float*  __restrict__ phases,
    const int2*   __restrict__ edges,
    uint*  __restrict__ cursors,
    uint2* __restrict__ records,
    int e_begin, int e_end, int cap, int nbp)
{
    __shared__ uint2 s_rec[RPB];        // 32 KB sorted record staging
    __shared__ uint  s_cnt[MAX_NB];     // 2 KB
    __shared__ uint  s_excl[MAX_NB];    // 2 KB
    __shared__ uint  s_base[MAX_NB];    // 2 KB
    __shared__ uint  s_wsum[PART_BLOCK / 64];

    const int tid = threadIdx.x;
    const int block_e0 = e_begin + blockIdx.x * EPB;   // always even (e_chunk even)

    // ---- 1. Load EPT edges as int4 (2 edges/load) + phases as float2 ----
    int   eu[EPT], ev[EPT];
    float ph[EPT];
    uint  vmask = 0u;
    {
        const int4v*   e4 = (const int4v*)edges;       // int4 g covers edges 2g, 2g+1
        const float2v* p2 = (const float2v*)phases;
        #pragma unroll
        for (int i = 0; i < EPT / 2; ++i) {
            int g  = (block_e0 >> 1) + i * PART_BLOCK + tid;
            int e0 = 2 * g;
            int4v   q = {0, 0, 0, 0};
            float2v p = {0.f, 0.f};
            if (e0 < e_end) {                          // pair never straddles e_end (even)
                q = __builtin_nontemporal_load(&e4[g]);
                p = __builtin_nontemporal_load(&p2[g]);
            }
            int j0 = 2 * i, j1 = 2 * i + 1;
            eu[j0] = q.x; ev[j0] = q.y;
            eu[j1] = q.z; ev[j1] = q.w;
            ph[j0] = p.x; ph[j1] = p.y;
            if (e0     < e_end) vmask |= 1u << j0;
            if (e0 + 1 < e_end) vmask |= 1u << j1;
        }
    }
    // ---- 2. Issue all gathers now; latency hides behind histogram+scan ----
    __half2 hu[EPT], hv[EPT];
    #pragma unroll
    for (int j = 0; j < EPT; ++j) {
        hu[j] = xh[eu[j]];
        hv[j] = xh[ev[j]];
    }

    // ---- 3. Histogram; the returned old value IS the local slot offset ----
    for (int b = tid; b < nbp; b += PART_BLOCK) s_cnt[b] = 0u;
    __syncthreads();

    uint metaU[EPT], metaV[EPT];
    #pragma unroll
    for (int j = 0; j < EPT; ++j) { metaU[j] = 0u; metaV[j] = 0u; }
    #pragma unroll
    for (int j = 0; j < EPT; ++j) {
        if ((vmask >> j) & 1u) {
            uint v  = (uint)ev[j];
            uint off = atomicAdd(&s_cnt[v >> NODE_SHIFT], 1u);
            metaV[j] = (off << 20) | v;                // off<=4095 (12b), v<2^20 (20b)
            uint u  = (uint)eu[j];
            off = atomicAdd(&s_cnt[u >> NODE_SHIFT], 1u);
            metaU[j] = (off << 20) | u;
        }
    }
    __syncthreads();

    // ---- 4. 2-barrier shuffle scan (each thread owns 2 buckets) ----
    {
        uint c0 = (2 * tid     < nbp) ? s_cnt[2 * tid]     : 0u;
        uint c1 = (2 * tid + 1 < nbp) ? s_cnt[2 * tid + 1] : 0u;
        uint sum = c0 + c1;
        uint incl = sum;
        #pragma unroll
        for (int d = 1; d < 64; d <<= 1) {
            uint o = __shfl_up(incl, (unsigned)d, 64);
            if ((tid & 63) >= d) incl += o;
        }
        int wv = tid >> 6;
        if ((tid & 63) == 63) s_wsum[wv] = incl;
        __syncthreads();
        uint wpref = 0;
        #pragma unroll
        for (int w = 0; w < PART_BLOCK / 64; ++w)
            if (w < wv) wpref += s_wsum[w];
        uint e0x = wpref + (incl - sum);               // exclusive prefix of bucket 2*tid
        if (2 * tid < nbp) {
            s_excl[2 * tid] = e0x;
            s_base[2 * tid] = c0 ? atomicAdd(&cursors[2 * tid], c0) : 0u;
        }
        if (2 * tid + 1 < nbp) {
            s_excl[2 * tid + 1] = e0x + c0;
            s_base[2 * tid + 1] = c1 ? atomicAdd(&cursors[2 * tid + 1], c1) : 0u;
        }
    }
    __syncthreads();

    // ---- 5. Compute rotations, place records sorted-by-bucket (no atomics) ----
    #pragma unroll
    for (int j = 0; j < EPT; ++j) {
        if ((vmask >> j) & 1u) {
            float s, c;
            __sincosf(ph[j], &s, &c);
            float2 fu = __half22float2(hu[j]);
            float2 fv = __half22float2(hv[j]);
            // contribution to out[v]: R(+p) @ x[u]
            float tux = fu.x * c - fu.y * s;
            float tuy = fu.x * s + fu.y * c;
            // contribution to out[u]: R(-p) @ x[v]
            float tvx = fv.x * c + fv.y * s;
            float tvy = fv.y * c - fv.x * s;
            {
                uint mv = metaV[j];
                uint v  = mv & 0xFFFFFu;
                uint b  = v >> NODE_SHIFT;
                uint slot = s_excl[b] + (mv >> 20);
                s_rec[slot] = make_uint2((b << 16) | (v & (BUCKET_NODES - 1)),
                                         pack_half2(tux, tuy));
            }
            {
                uint mu = metaU[j];
                uint u  = mu & 0xFFFFFu;
                uint b  = u >> NODE_SHIFT;
                uint slot = s_excl[b] + (mu >> 20);
                s_rec[slot] = make_uint2((b << 16) | (u & (BUCKET_NODES - 1)),
                                         pack_half2(tvx, tvy));
            }
        }
    }
    __syncthreads();

    // ---- 6. Coalesced flush (nontemporal: keep L2 for the xh table) ----
    int valid_edges = e_end - block_e0;
    if (valid_edges > EPB) valid_edges = EPB;
    int total = 2 * valid_edges;
    for (int s = tid; s < total; s += PART_BLOCK) {
        uint2 r = s_rec[s];
        uint b = r.x >> 16;
        uint g = s_base[b] + ((uint)s - s_excl[b]);
        if (g < (uint)cap) {
            uint2v rv = { r.x, r.y };
            __builtin_nontemporal_store(rv, (uint2v*)&records[(size_t)b * cap + g]);
        }
    }
}

static __device__ __forceinline__ void acc_record(int* accX, int* accY, uint key, uint payload) {
    union { uint u; __half2 h; } cvt; cvt.u = payload;
    float2 f = __half22float2(cvt.h);
    uint node = key & 0xFFFFu;
    atomicAdd(&accX[node], __float2int_rn(f.x * FIX_SCALE));
    atomicAdd(&accY[node], __float2int_rn(f.y * FIX_SCALE));
}

__global__ __launch_bounds__(ACC_BLOCK) void rot_accumulate(
    const float2* __restrict__ x2,
    const uint*   __restrict__ cursors,
    const uint2*  __restrict__ records,
    float2* __restrict__ out2,
    int cap, int n_nodes, int first_chunk)
{
    __shared__ int accX[BUCKET_NODES];
    __shared__ int accY[BUCKET_NODES];
    for (int i = threadIdx.x; i < BUCKET_NODES; i += ACC_BLOCK) {
        accX[i] = 0; accY[i] = 0;
    }
    __syncthreads();

    const int b = blockIdx.x;
    uint cnt = cursors[b];
    if (cnt > (uint)cap) cnt = (uint)cap;
    const uint4v* rec4 = (const uint4v*)(records + (size_t)b * cap);
    uint n4 = cnt >> 1;                     // number of uint4 elements
    uint tid = threadIdx.x;

    // 8-deep batched loads: issue all 8 uint4 loads, then consume.
    for (uint i0 = tid; i0 < n4; i0 += (uint)(ACC_UN * ACC_BLOCK)) {
        uint4v r[ACC_UN];
        #pragma unroll
        for (int j = 0; j < ACC_UN; ++j) {
            uint idx = i0 + (uint)j * ACC_BLOCK;
            uint4v z = {0, 0, 0, 0};
            r[j] = (idx < n4) ? __builtin_nontemporal_load(&rec4[idx]) : z;
        }
        #pragma unroll
        for (int j = 0; j < ACC_UN; ++j) {
            uint idx = i0 + (uint)j * ACC_BLOCK;
            if (idx < n4) {                 // guard: avoid same-address atomic storms
                acc_record(accX, accY, r[j].x, r[j].y);
                acc_record(accX, accY, r[j].z, r[j].w);
            }
        }
    }
    if ((cnt & 1u) && tid == 0) {
        const uint2* rec = records + (size_t)b * cap;
        uint2 r = rec[cnt - 1];
        acc_record(accX, accY, r.x, r.y);
    }
    __syncthreads();

    const int node0 = b << NODE_SHIFT;
    for (int i = threadIdx.x; i < BUCKET_NODES; i += ACC_BLOCK) {
        int node = node0 + i;
        if (node < n_nodes) {
            float ax = (float)accX[i] * INV_FIX;
            float ay = (float)accY[i] * INV_FIX;
            float2 base = first_chunk ? x2[node] : out2[node];
            out2[node] = make_float2(base.x + ax, base.y + ay);
        }
    }
}

// ---------------- fallback (atomic path, used only if ws too small) ----------

__global__ __launch_bounds__(256) void rot_init_out(const float* __restrict__ x,
                                                    float* __restrict__ out, int n) {
    int i = blockIdx.x * blockDim.x + threadIdx.x;
    if (i < n) out[i] = x[i];
}

__global__ __launch_bounds__(256) void rot_edge_atomic(
    const float2* __restrict__ x2, const float* __restrict__ phases,
    const int2* __restrict__ edges, float* __restrict__ out, int n_edges)
{
    int e = blockIdx.x * blockDim.x + threadIdx.x;
    if (e >= n_edges) return;
    int2 uv = edges[e];
    float p = phases[e];
    float s = __sinf(p), c = __cosf(p);
    float2 hu = x2[uv.x], hv = x2[uv.y];
    unsafeAtomicAdd(&out[2 * uv.y + 0], hu.x * c - hu.y * s);
    unsafeAtomicAdd(&out[2 * uv.y + 1], hu.x * s + hu.y * c);
    unsafeAtomicAdd(&out[2 * uv.x + 0], hv.x * c + hv.y * s);
    unsafeAtomicAdd(&out[2 * uv.x + 1], hv.y * c - hv.x * s);
}

// -----------------------------------------------------------------------------

extern "C" void kernel_launch(void* const* d_in, const int* in_sizes, int n_in,
                              void* d_out, int out_size, void* d_ws, size_t ws_size,
                              hipStream_t stream) {
    const float* x      = (const float*)d_in[0];
    const float* phases = (const float*)d_in[1];
    const int2*  edges  = (const int2*)d_in[2];
    float* out = (float*)d_out;

    const int n_nodes = out_size / 2;
    const int E       = in_sizes[1];
    const int nb      = (n_nodes + BUCKET_NODES - 1) >> NODE_SHIFT;

    // Pick smallest chunk count k whose records + cursors + xh table fit in ws.
    int chosen_k = 0, chosen_cap = 0;
    if (d_ws && nb <= MAX_NB) {
        const int ks[5] = {1, 2, 4, 8, 16};
        for (int i = 0; i < 5; ++i) {
            int k = ks[i];
            long long e_chunk = ((long long)E + k - 1) / k;
            double m = (double)(2 * e_chunk) / (double)nb;
            long long cap = (long long)(m + 10.0 * sqrt(m) + 64.0);
            cap = (cap + 255) & ~255LL;
            long long need = (long long)nb * cap * 8       // records
                           + (((long long)nb * 4 + 255) & ~255LL)  // cursors
                           + (long long)n_nodes * 4 + 512;         // xh table
            if ((size_t)need <= ws_size) { chosen_k = k; chosen_cap = (int)cap; break; }
        }
    }

    if (chosen_k == 0) {
        rot_init_out<<<(out_size + 255) / 256, 256, 0, stream>>>(x, out, out_size);
        rot_edge_atomic<<<(E + 255) / 256, 256, 0, stream>>>(
            (const float2*)x, phases, edges, out, E);
        return;
    }

    const int cap = chosen_cap;
    uint2*   records = (uint2*)d_ws;
    size_t   off = (size_t)nb * cap * 8;
    uint*    cursors = (uint*)((char*)d_ws + off);
    off += ((size_t)nb * 4 + 255) & ~(size_t)255;
    __half2* xh = (__half2*)((char*)d_ws + off);

    // Build the 4 MB half2 gather table (fits per-XCD L2).
    rot_make_xh<<<(n_nodes + 255) / 256, 256, 0, stream>>>((const float2*)x, xh, n_nodes);

    int e_chunk = (E + chosen_k - 1) / chosen_k;
    e_chunk = (e_chunk + 1) & ~1;            // keep chunk boundaries even (int4 loads)
    for (int cidx = 0; cidx < chosen_k; ++cidx) {
        int e0 = cidx * e_chunk;
        int e1 = (e0 + e_chunk < E) ? (e0 + e_chunk) : E;
        if (e0 >= e1) break;

        rot_zero_cursors<<<(nb + 255) / 256, 256, 0, stream>>>(cursors, nb);

        int nblk = (e1 - e0 + EPB - 1) / EPB;
        rot_partition<<<nblk, PART_BLOCK, 0, stream>>>(
            xh, phases, edges, cursors, records, e0, e1, cap, nb);

        rot_accumulate<<<nb, ACC_BLOCK, 0, stream>>>(
            (const float2*)x, cursors, records, (float2*)out, cap, n_nodes,
            cidx == 0 ? 1 : 0);
    }
}